// Round 15
// baseline (120.284 us; speedup 1.0000x reference)
//
#include <hip/hip_runtime.h>
#include <hip/hip_bf16.h>
#include <stdint.h>

#define DEV __device__ __forceinline__

typedef unsigned short u16;
typedef unsigned int   u32;
typedef __attribute__((ext_vector_type(8))) short bf16x8;   // 8 bf16 = 4 VGPRs
typedef __attribute__((ext_vector_type(4))) float f32x4;
typedef __attribute__((ext_vector_type(4))) u32   u32x4;
typedef __attribute__((ext_vector_type(2))) u32   u32x2;

// ---- numeric helpers -------------------------------------------------------
DEV u16 f2bf(float f) {            // RNE f32 -> bf16
  u32 u = __builtin_bit_cast(u32, f);
  u = (u + 0x7fffu + ((u >> 16) & 1u)) >> 16;
  return (u16)u;
}
DEV float bf2f(u16 h) { return __builtin_bit_cast(float, (u32)h << 16); }
DEV u32 pk2(float a, float b) {    // pack 2 f32 -> 2 bf16 in one u32 (RNE)
  u32 x = __builtin_bit_cast(u32, a), y = __builtin_bit_cast(u32, b);
  x = (x + 0x7fffu + ((x >> 16) & 1u)) >> 16;
  y = (y + 0x7fffu + ((y >> 16) & 1u)) >> 16;
  return x | (y << 16);
}
DEV u32 cvtpk(float lo, float hi) {  // 1-instr RNE pack (same semantics as pk2)
  u32 r;
  asm("v_cvt_pk_bf16_f32 %0, %1, %2" : "=v"(r) : "v"(lo), "v"(hi));
  return r;
}
DEV f32x4 mfma16(bf16x8 a, bf16x8 b, f32x4 c) {
  return __builtin_amdgcn_mfma_f32_16x16x32_bf16(a, b, c, 0, 0, 0);
}
DEV void gload16(const void* g, void* l) {   // global -> LDS direct, 16B/lane
  __builtin_amdgcn_global_load_lds(
      (const __attribute__((address_space(1))) void*)g,
      (__attribute__((address_space(3))) void*)l, 16, 0, 0);
}

// ---- problem constants -----------------------------------------------------
// B=2 T=2048 DIM=1024 HEADS=16 HEAD_DIM=64; tokens = 4096
// workspace layout (bytes):
//  XB      0         x as bf16            [4096][1024]
//  WQKVT   8388608   Wqkv^T bf16          [3072][1024]
//  WPROJT  14680064  Wproj^T bf16         [1024][1024]
//  QR      41943040  roped*scale Q bf16   [32][2048][64]  (d-PERMUTED: natural f)
//  KR      50331648  roped K bf16         [32][2048][64]  (d-PERMUTED: natural f)
//  VT      58720256  V^T bf16             [32][64][2048]
//  AO      67108864  attn out bf16        [4096][1024]
//  SIN     75497472  f32 [2048][32]
//  COS     75759616  f32 [2048][32]
// NOTE: QR/KR store rope outputs at NATURAL column f (even f: x1*cs-x2*sn,
// odd f: x1*sn+x2*cs) instead of the reference's [dp | 32+dp] split. QK^T is
// invariant under any d-permutation applied to BOTH operands, so k_attn is
// unchanged and scores are bit-identical in structure.

// ---- merged prep kernel ----------------------------------------------------
__global__ __launch_bounds__(256) void k_prep(const float* __restrict__ x,
                                              u16* __restrict__ XB,
                                              const float* __restrict__ Wqkv,
                                              u16* __restrict__ WQKVT,
                                              const float* __restrict__ Wproj,
                                              u16* __restrict__ WPROJT,
                                              const int* __restrict__ posp,
                                              float* __restrict__ sint,
                                              float* __restrict__ cost) {
  __shared__ float t[32][33];
  int bid = blockIdx.x;
  int tid = threadIdx.x;

  if (bid < 2048) {                        // ---- cvt x -> bf16
    size_t i = ((size_t)bid * 256 + tid) * 8;
    float4 a = *(const float4*)(x + i);
    float4 b = *(const float4*)(x + i + 4);
    u32x4 o = { pk2(a.x, a.y), pk2(a.z, a.w), pk2(b.x, b.y), pk2(b.z, b.w) };
    *(u32x4*)(XB + i) = o;
    return;
  }
  if (bid < 6144) {                        // ---- W transpose+cvt
    const float* W; u16* WT; int Ndim, idx;
    if (bid < 5120) { W = Wqkv;  WT = WQKVT;  Ndim = 3072; idx = bid - 2048; }
    else            { W = Wproj; WT = WPROJT; Ndim = 1024; idx = bid - 5120; }
    int bk = idx & 31;
    int bn = idx >> 5;
    int k0 = bk * 32, n0 = bn * 32;
    int tx = tid & 31, ty = tid >> 5;      // ty 0..7
#pragma unroll
    for (int i = 0; i < 4; ++i)
      t[ty + 8 * i][tx] = W[(size_t)(k0 + ty + 8 * i) * Ndim + n0 + tx];
    __syncthreads();
#pragma unroll
    for (int i = 0; i < 4; ++i) {
      int n = ty + 8 * i;
      WT[(size_t)(n0 + n) * 1024 + k0 + tx] = f2bf(t[tx][n]);
    }
    return;
  }
  // ---- rope tables
  int i = (bid - 6144) * 256 + tid;        // 65536 = 2048*32
  int tt = i >> 5, d = i & 31;
  float theta = exp2f(-(float)d * (13.2877123795494f / 32.0f));
  float ang = (float)(posp[0] + tt) * theta;
  sint[i] = sinf(ang);
  cost[i] = cosf(ang);
}

// ---- QKV GEMM with fused RoPE / V-transpose epilogue -----------------------
// Main loop = m97 single-barrier structure. Q/K epilogue stores rope results
// in the d-PERMUTED layout (natural col f): even lanes compute BOTH halves of
// their pair (partner value via __shfl_xor(v,1)) and store ONE u32 at col f —
// 32x 4B stores in contiguous 32B runs vs R13's 64x scattered 2B stores.
__global__ __launch_bounds__(256, 3) void k_gemm_qkv(const u16* __restrict__ A,
                                                     const u16* __restrict__ BT,
                                                     const float* __restrict__ bias,
                                                     u16* __restrict__ QR,
                                                     u16* __restrict__ KR,
                                                     u16* __restrict__ VT,
                                                     const float* __restrict__ sint,
                                                     const float* __restrict__ cost) {
  constexpr int K = 1024;
  int bm = blockIdx.x & 31;             // M/128 = 32
  int bn = blockIdx.x >> 5;             // 0..23
  int m0 = bm * 128, n0 = bn * 128;
  int tid = threadIdx.x, lane = tid & 63, w = tid >> 6;
  int g = lane >> 4, l15 = lane & 15;
  int wr = w >> 1, wc = w & 1;

  __shared__ u16 Alds[2][128 * 32];     // 8KB per buf
  __shared__ u16 Blds[2][128 * 32];

  f32x4 acc[4][4] = {};

  int rowW = w * 16 + (lane >> 2);
  int cSrc = (lane & 3) ^ ((lane >> 3) & 3);
  const u16* Ag0 = A  + (size_t)(m0 + rowW) * K + cSrc * 8;
  const u16* Ag1 = A  + (size_t)(m0 + 64 + rowW) * K + cSrc * 8;
  const u16* Bg0 = BT + (size_t)(n0 + rowW) * K + cSrc * 8;
  const u16* Bg1 = BT + (size_t)(n0 + 64 + rowW) * K + cSrc * 8;

  auto stage = [&](int k0, int buf) {
    gload16(Ag0 + k0, (char*)&Alds[buf][0] + w * 1024);
    gload16(Ag1 + k0, (char*)&Alds[buf][0] + 4096 + w * 1024);
    gload16(Bg0 + k0, (char*)&Blds[buf][0] + w * 1024);
    gload16(Bg1 + k0, (char*)&Blds[buf][0] + 4096 + w * 1024);
  };

  stage(0, 0);
  __syncthreads();
  int cur = 0;

#pragma unroll 1
  for (int it = 0; it < 32; ++it) {
    if (it + 1 < 32) stage((it + 1) * 32, cur ^ 1);  // loads fly under compute
    const char* Ab = (const char*)&Alds[cur][0];
    const char* Bb = (const char*)&Blds[cur][0];
    bf16x8 af[4], bf_[4];
#pragma unroll
    for (int m = 0; m < 4; ++m) {
      int r = wr * 64 + m * 16 + l15;
      af[m] = *(const bf16x8*)(Ab + r * 64 + ((g ^ ((r >> 1) & 3)) << 4));
    }
#pragma unroll
    for (int n = 0; n < 4; ++n) {
      int r = wc * 64 + n * 16 + l15;
      bf_[n] = *(const bf16x8*)(Bb + r * 64 + ((g ^ ((r >> 1) & 3)) << 4));
    }
#pragma unroll
    for (int m = 0; m < 4; ++m)
#pragma unroll
      for (int n = 0; n < 4; ++n)
        acc[m][n] = mfma16(af[m], bf_[n], acc[m][n]);
    __syncthreads();                    // single barrier: drains loads + reads
    cur ^= 1;
  }

  int bq = m0 >> 11;                    // batch index (uniform per tile)

  if (bn >= 16) {
    // ---- V: transposed store into VT[bh][d][t], 4 tokens packed per store
#pragma unroll
    for (int m = 0; m < 4; ++m) {
      int rowb = m0 + wr * 64 + m * 16 + 4 * g;
      int tt = rowb & 2047;
#pragma unroll
      for (int n = 0; n < 4; ++n) {
        int colv = n0 + wc * 64 + n * 16 + l15 - 2048;
        float bv = bias[colv + 2048];
        int h = colv >> 6, d = colv & 63;
        int bh = bq * 16 + h;
        u32x2 o = { pk2(acc[m][n][0] + bv, acc[m][n][1] + bv),
                    pk2(acc[m][n][2] + bv, acc[m][n][3] + bv) };
        *(u32x2*)(VT + ((size_t)(bh * 64 + d)) * 2048 + tt) = o;
      }
    }
  } else {
    // ---- Q/K: fused RoPE, d-PERMUTED output (natural col f).
    // Even lane (f even): v=x1, partner pv=x2. Stores u32 {x1*cs-x2*sn,
    // x1*sn+x2*cs} at col f. Odd lanes only feed the shuffle.
    bool isQ = (bn < 8);
    u16* OUT = isQ ? QR : KR;
    int cofs = isQ ? 0 : 1024;
    float sc = isQ ? 0.125f : 1.0f;
    bool evenl = (lane & 1) == 0;
#pragma unroll
    for (int m = 0; m < 4; ++m) {
      int rowb = m0 + wr * 64 + m * 16 + 4 * g;
#pragma unroll
      for (int n = 0; n < 4; ++n) {
        int col = n0 + wc * 64 + n * 16 + l15 - cofs;
        float bv = bias[col + cofs];
        int h = col >> 6, f = col & 63;
        int bh = bq * 16 + h;
        int dp = f >> 1;
#pragma unroll
        for (int j = 0; j < 4; ++j) {
          int tt = (rowb + j) & 2047;
          float v = acc[m][n][j] + bv;
          float pv = __shfl_xor(v, 1);       // partner column value
          if (evenl) {
            float sn = sint[tt * 32 + dp], cs = cost[tt * 32 + dp];
            float oe = sc * (v * cs - pv * sn);
            float oo = sc * (v * sn + pv * cs);
            *(u32*)(OUT + ((size_t)(bh * 2048 + tt)) * 64 + f) = pk2(oe, oo);
          }
        }
      }
    }
  }
}

// ---- proj GEMM: C[4096][1024] f32 = AO @ WPROJT^T + bias (unchanged) -------
__global__ __launch_bounds__(256, 3) void k_gemm_proj(const u16* __restrict__ A,
                                                      const u16* __restrict__ BT,
                                                      const float* __restrict__ bias,
                                                      float* __restrict__ Cout) {
  constexpr int K = 1024, N = 1024;
  int bm = blockIdx.x & 31;
  int bn = blockIdx.x >> 5;
  int m0 = bm * 128, n0 = bn * 128;
  int tid = threadIdx.x, lane = tid & 63, w = tid >> 6;
  int g = lane >> 4, l15 = lane & 15;
  int wr = w >> 1, wc = w & 1;

  __shared__ u16 Alds[2][128 * 32];
  __shared__ u16 Blds[2][128 * 32];

  f32x4 acc[4][4] = {};

  int rowW = w * 16 + (lane >> 2);
  int cSrc = (lane & 3) ^ ((lane >> 3) & 3);
  const u16* Ag0 = A  + (size_t)(m0 + rowW) * K + cSrc * 8;
  const u16* Ag1 = A  + (size_t)(m0 + 64 + rowW) * K + cSrc * 8;
  const u16* Bg0 = BT + (size_t)(n0 + rowW) * K + cSrc * 8;
  const u16* Bg1 = BT + (size_t)(n0 + 64 + rowW) * K + cSrc * 8;

  auto stage = [&](int k0, int buf) {
    gload16(Ag0 + k0, (char*)&Alds[buf][0] + w * 1024);
    gload16(Ag1 + k0, (char*)&Alds[buf][0] + 4096 + w * 1024);
    gload16(Bg0 + k0, (char*)&Blds[buf][0] + w * 1024);
    gload16(Bg1 + k0, (char*)&Blds[buf][0] + 4096 + w * 1024);
  };

  stage(0, 0);
  __syncthreads();
  int cur = 0;

#pragma unroll 1
  for (int it = 0; it < 32; ++it) {
    if (it + 1 < 32) stage((it + 1) * 32, cur ^ 1);
    const char* Ab = (const char*)&Alds[cur][0];
    const char* Bb = (const char*)&Blds[cur][0];
    bf16x8 af[4], bf_[4];
#pragma unroll
    for (int m = 0; m < 4; ++m) {
      int r = wr * 64 + m * 16 + l15;
      af[m] = *(const bf16x8*)(Ab + r * 64 + ((g ^ ((r >> 1) & 3)) << 4));
    }
#pragma unroll
    for (int n = 0; n < 4; ++n) {
      int r = wc * 64 + n * 16 + l15;
      bf_[n] = *(const bf16x8*)(Bb + r * 64 + ((g ^ ((r >> 1) & 3)) << 4));
    }
#pragma unroll
    for (int m = 0; m < 4; ++m)
#pragma unroll
      for (int n = 0; n < 4; ++n)
        acc[m][n] = mfma16(af[m], bf_[n], acc[m][n]);
    __syncthreads();
    cur ^= 1;
  }

#pragma unroll
  for (int m = 0; m < 4; ++m) {
    int rowb = m0 + wr * 64 + m * 16 + 4 * g;
#pragma unroll
    for (int n = 0; n < 4; ++n) {
      int col = n0 + wc * 64 + n * 16 + l15;
      float bv = bias[col];
#pragma unroll
      for (int j = 0; j < 4; ++j)
        Cout[(size_t)(rowb + j) * N + col] = acc[m][n][j] + bv;
    }
  }
}

// ---- causal flash attention (R5/R13 verbatim — proven 46 us) ---------------
__global__ __launch_bounds__(256, 4) void k_attn(const u16* __restrict__ QR,
                                                 const u16* __restrict__ KR,
                                                 const u16* __restrict__ VT,
                                                 u16* __restrict__ AO) {
  int tid = threadIdx.x;
  int w = tid >> 6, lane = tid & 63;
  int g = lane >> 4, l15 = lane & 15;
  int l7 = l15 & 7, g2 = g >> 1;

  int idx = blockIdx.x;
  int tt = 31 - (idx >> 5);          // q-tile 31..0 (heavy first)
  int bh = idx & 31;                 // bh mod 8 = XCD slot -> 4 bh per XCD
  int nt = tt + 1;                   // 64-key tiles to process
  int b = bh >> 4, h = bh & 15;
  int q0 = tt * 64 + w * 16;         // wave's 16-row subtile
  int qa = q0 + l15;

  const u16* Kg = KR + (size_t)bh * 2048 * 64;
  const u16* Vg = VT + (size_t)bh * 64 * 2048;

  __shared__ u16 Klds[2][64 * 64];   // 8KB/buf: [key][64 d], swizzled
  __shared__ u16 Vlds[2][64 * 64];   // 8KB/buf: [d][64 key], swizzled

  const u16* Qr = QR + ((size_t)bh * 2048 + q0 + l15) * 64 + 8 * g;
  bf16x8 qf0 = *(const bf16x8*)(Qr);
  bf16x8 qf1 = *(const bf16x8*)(Qr + 32);

  f32x4 o[4] = {};
  float m = -1e30f, l = 0.f;

  // hoisted LDS read constants
  int kx0 = ((g ^ l7) << 4);                 // K frag chunk offsets (bytes)
  int kx1 = (((4 + g) ^ l7) << 4);
  int vx0 = ((g2 ^ l7) << 4);                // V chunks s2=0: {g2, 2+g2}
  int vx1 = (((2 + g2) ^ l7) << 4);
  int vx2 = (((4 + g2) ^ l7) << 4);          // s2=1: {4+g2, 6+g2}
  int vx3 = (((6 + g2) ^ l7) << 4);
  int vbase = l15 * 128 + ((g & 1) << 3);

  // staging: 256 threads cover 64 rows x 8 chunks in 2 issues (K and V each)
  int rstg = lane >> 3;                      // 0..7
  int cswz = (lane & 7) ^ rstg;              // pre-swizzled source chunk

  auto stage = [&](int kt, int buf) {
#pragma unroll
    for (int j = 0; j < 2; ++j) {
      int r = j * 32 + w * 8 + rstg;
      gload16(Kg + (size_t)(kt * 64 + r) * 64 + cswz * 8,
              &Klds[buf][(j * 32 + w * 8) * 64]);
      gload16(Vg + (size_t)r * 2048 + kt * 64 + cswz * 8,
              &Vlds[buf][(j * 32 + w * 8) * 64]);
    }
  };

  stage(0, 0);
  __syncthreads();
  int cur = 0;

  for (int t = 0; t < nt; ++t) {
    if (t + 1 < nt) stage(t + 1, cur ^ 1);   // async prefetch next tile
    const char* Kb = (const char*)&Klds[cur][0];
    const char* Vb = (const char*)&Vlds[cur][0];

    // S^T = K.Q (64 keys x 16 q)
    f32x4 sb[4];
    __builtin_amdgcn_s_setprio(1);
#pragma unroll
    for (int blk = 0; blk < 4; ++blk) {
      const char* kb = Kb + blk * 2048 + l15 * 128;
      bf16x8 k0 = *(const bf16x8*)(kb + kx0);
      bf16x8 k1 = *(const bf16x8*)(kb + kx1);
      f32x4 z = { 0.f, 0.f, 0.f, 0.f };
      z = mfma16(k0, qf0, z);
      sb[blk] = mfma16(k1, qf1, z);
    }
    __builtin_amdgcn_s_setprio(0);

    if (t == nt - 1) {               // causal mask, final tile only
      int tk0 = t * 64;
#pragma unroll
      for (int blk = 0; blk < 4; ++blk)
#pragma unroll
        for (int j = 0; j < 4; ++j) {
          int tk = tk0 + blk * 16 + 4 * g + j;
          if (tk > qa) sb[blk][j] = -1e30f;
        }
    }

    // online softmax (defer-max) + PV
    float mx = fmaxf(fmaxf(fmaxf(sb[0][0], sb[0][1]), fmaxf(sb[0][2], sb[0][3])),
                     fmaxf(fmaxf(sb[1][0], sb[1][1]), fmaxf(sb[1][2], sb[1][3])));
    mx = fmaxf(mx, fmaxf(fmaxf(fmaxf(sb[2][0], sb[2][1]), fmaxf(sb[2][2], sb[2][3])),
                         fmaxf(fmaxf(sb[3][0], sb[3][1]), fmaxf(sb[3][2], sb[3][3]))));
    mx = fmaxf(mx, __shfl_xor(mx, 16));
    mx = fmaxf(mx, __shfl_xor(mx, 32));
    if (!__all(mx <= m + 8.0f)) {
      float mnew = fmaxf(m, mx);
      float a = __builtin_amdgcn_exp2f((m - mnew) * 1.44269504f);
      l *= a;
#pragma unroll
      for (int d = 0; d < 4; ++d) o[d] *= a;
      m = mnew;
    }
    float em = m * 1.44269504f;
    float p[4][4];
    float ps = 0.f;
#pragma unroll
    for (int blk = 0; blk < 4; ++blk)
#pragma unroll
      for (int j = 0; j < 4; ++j) {
        float pv = __builtin_amdgcn_exp2f(__builtin_fmaf(sb[blk][j], 1.44269504f, -em));
        p[blk][j] = pv;
        ps += pv;
      }
    l += ps;

    __builtin_amdgcn_s_setprio(1);
#pragma unroll
    for (int s2 = 0; s2 < 2; ++s2) {
      u32x4 pw = { cvtpk(p[2 * s2][0], p[2 * s2][1]),
                   cvtpk(p[2 * s2][2], p[2 * s2][3]),
                   cvtpk(p[2 * s2 + 1][0], p[2 * s2 + 1][1]),
                   cvtpk(p[2 * s2 + 1][2], p[2 * s2 + 1][3]) };
      bf16x8 pb = __builtin_bit_cast(bf16x8, pw);
      int cl = s2 ? vx2 : vx0;
      int ch = s2 ? vx3 : vx1;
#pragma unroll
      for (int dblk = 0; dblk < 4; ++dblk) {
        uint2 lo = *(const uint2*)(Vb + vbase + dblk * 2048 + cl);
        uint2 hi = *(const uint2*)(Vb + vbase + dblk * 2048 + ch);
        bf16x8 va = __builtin_bit_cast(bf16x8, u32x4{ lo.x, lo.y, hi.x, hi.y });
        o[dblk] = mfma16(va, pb, o[dblk]);
      }
    }
    __builtin_amdgcn_s_setprio(0);

    __syncthreads();
    cur ^= 1;
  }

  float lt = l + __shfl_xor(l, 16);
  lt += __shfl_xor(lt, 32);
  float inv = 1.0f / lt;
  u16* orow = AO + ((size_t)b * 2048 + q0 + l15) * 1024 + h * 64 + 4 * g;
#pragma unroll
  for (int dblk = 0; dblk < 4; ++dblk) {
    u32x2 ov = { cvtpk(o[dblk][0] * inv, o[dblk][1] * inv),
                 cvtpk(o[dblk][2] * inv, o[dblk][3] * inv) };
    *(u32x2*)(orow + dblk * 16) = ov;
  }
}

// ---- launcher ---------------------------------------------------------------
extern "C" void kernel_launch(void* const* d_in, const int* in_sizes, int n_in,
                              void* d_out, int out_size, void* d_ws, size_t ws_size,
                              hipStream_t stream) {
  (void)in_sizes; (void)n_in; (void)out_size; (void)ws_size;
  const float* x     = (const float*)d_in[0];
  const float* Wqkv  = (const float*)d_in[1];
  const float* bqkv  = (const float*)d_in[2];
  const float* Wproj = (const float*)d_in[3];
  const float* bproj = (const float*)d_in[4];
  const int*   pos   = (const int*)d_in[5];

  char* ws = (char*)d_ws;
  u16*   XB     = (u16*)(ws + 0);
  u16*   WQKVT  = (u16*)(ws + 8388608);
  u16*   WPROJT = (u16*)(ws + 14680064);
  u16*   QR     = (u16*)(ws + 41943040);
  u16*   KR     = (u16*)(ws + 50331648);
  u16*   VT     = (u16*)(ws + 58720256);
  u16*   AO     = (u16*)(ws + 67108864);
  float* SIN    = (float*)(ws + 75497472);
  float* COS    = (float*)(ws + 75759616);

  k_prep<<<6400, 256, 0, stream>>>(x, XB, Wqkv, WQKVT, Wproj, WPROJT, pos, SIN, COS);
  k_gemm_qkv<<<32 * 24, 256, 0, stream>>>(XB, WQKVT, bqkv, QR, KR, VT, SIN, COS);
  k_attn<<<1024, 256, 0, stream>>>(QR, KR, VT, AO);
  k_gemm_proj<<<32 * 8, 256, 0, stream>>>(AO, WPROJT, bproj, (float*)d_out);
}

// Round 16
// 113.156 us; speedup vs baseline: 1.0630x; 1.0630x over previous
//
#include <hip/hip_runtime.h>
#include <hip/hip_bf16.h>
#include <stdint.h>

#define DEV __device__ __forceinline__

typedef unsigned short u16;
typedef unsigned int   u32;
typedef __attribute__((ext_vector_type(8))) short bf16x8;   // 8 bf16 = 4 VGPRs
typedef __attribute__((ext_vector_type(4))) float f32x4;
typedef __attribute__((ext_vector_type(4))) u32   u32x4;
typedef __attribute__((ext_vector_type(2))) u32   u32x2;

// ---- numeric helpers -------------------------------------------------------
DEV u16 f2bf(float f) {            // RNE f32 -> bf16
  u32 u = __builtin_bit_cast(u32, f);
  u = (u + 0x7fffu + ((u >> 16) & 1u)) >> 16;
  return (u16)u;
}
DEV float bf2f(u16 h) { return __builtin_bit_cast(float, (u32)h << 16); }
DEV u32 pk2(float a, float b) {    // pack 2 f32 -> 2 bf16 in one u32 (RNE)
  u32 x = __builtin_bit_cast(u32, a), y = __builtin_bit_cast(u32, b);
  x = (x + 0x7fffu + ((x >> 16) & 1u)) >> 16;
  y = (y + 0x7fffu + ((y >> 16) & 1u)) >> 16;
  return x | (y << 16);
}
DEV u32 cvtpk(float lo, float hi) {  // 1-instr RNE pack (same semantics as pk2)
  u32 r;
  asm("v_cvt_pk_bf16_f32 %0, %1, %2" : "=v"(r) : "v"(lo), "v"(hi));
  return r;
}
DEV f32x4 mfma16(bf16x8 a, bf16x8 b, f32x4 c) {
  return __builtin_amdgcn_mfma_f32_16x16x32_bf16(a, b, c, 0, 0, 0);
}
DEV void gload16(const void* g, void* l) {   // global -> LDS direct, 16B/lane
  __builtin_amdgcn_global_load_lds(
      (const __attribute__((address_space(1))) void*)g,
      (__attribute__((address_space(3))) void*)l, 16, 0, 0);
}

// ---- problem constants -----------------------------------------------------
// B=2 T=2048 DIM=1024 HEADS=16 HEAD_DIM=64; tokens = 4096
// workspace layout (bytes):
//  XB      0         x as bf16            [4096][1024]
//  WQKVT   8388608   Wqkv^T bf16          [3072][1024]
//  WPROJT  14680064  Wproj^T bf16         [1024][1024]
//  QR      41943040  roped*scale Q bf16   [32][2048][64]
//  KR      50331648  roped K bf16         [32][2048][64]
//  VT      58720256  V^T bf16             [32][64][2048]
//  AO      67108864  attn out bf16        [4096][1024]
//  SIN     75497472  f32 [2048][32]
//  COS     75759616  f32 [2048][32]

// ---- merged prep kernel ----------------------------------------------------
__global__ __launch_bounds__(256) void k_prep(const float* __restrict__ x,
                                              u16* __restrict__ XB,
                                              const float* __restrict__ Wqkv,
                                              u16* __restrict__ WQKVT,
                                              const float* __restrict__ Wproj,
                                              u16* __restrict__ WPROJT,
                                              const int* __restrict__ posp,
                                              float* __restrict__ sint,
                                              float* __restrict__ cost) {
  __shared__ float t[32][33];
  int bid = blockIdx.x;
  int tid = threadIdx.x;

  if (bid < 2048) {                        // ---- cvt x -> bf16
    size_t i = ((size_t)bid * 256 + tid) * 8;
    float4 a = *(const float4*)(x + i);
    float4 b = *(const float4*)(x + i + 4);
    u32x4 o = { pk2(a.x, a.y), pk2(a.z, a.w), pk2(b.x, b.y), pk2(b.z, b.w) };
    *(u32x4*)(XB + i) = o;
    return;
  }
  if (bid < 6144) {                        // ---- W transpose+cvt
    const float* W; u16* WT; int Ndim, idx;
    if (bid < 5120) { W = Wqkv;  WT = WQKVT;  Ndim = 3072; idx = bid - 2048; }
    else            { W = Wproj; WT = WPROJT; Ndim = 1024; idx = bid - 5120; }
    int bk = idx & 31;
    int bn = idx >> 5;
    int k0 = bk * 32, n0 = bn * 32;
    int tx = tid & 31, ty = tid >> 5;      // ty 0..7
#pragma unroll
    for (int i = 0; i < 4; ++i)
      t[ty + 8 * i][tx] = W[(size_t)(k0 + ty + 8 * i) * Ndim + n0 + tx];
    __syncthreads();
#pragma unroll
    for (int i = 0; i < 4; ++i) {
      int n = ty + 8 * i;
      WT[(size_t)(n0 + n) * 1024 + k0 + tx] = f2bf(t[tx][n]);
    }
    return;
  }
  // ---- rope tables
  int i = (bid - 6144) * 256 + tid;        // 65536 = 2048*32
  int tt = i >> 5, d = i & 31;
  float theta = exp2f(-(float)d * (13.2877123795494f / 32.0f));
  float ang = (float)(posp[0] + tt) * theta;
  sint[i] = sinf(ang);
  cost[i] = cosf(ang);
}

// ---- QKV GEMM with fused RoPE / V-transpose epilogue (R13 exact) -----------
__global__ __launch_bounds__(256, 3) void k_gemm_qkv(const u16* __restrict__ A,
                                                     const u16* __restrict__ BT,
                                                     const float* __restrict__ bias,
                                                     u16* __restrict__ QR,
                                                     u16* __restrict__ KR,
                                                     u16* __restrict__ VT,
                                                     const float* __restrict__ sint,
                                                     const float* __restrict__ cost) {
  constexpr int K = 1024;
  int bm = blockIdx.x & 31;             // M/128 = 32
  int bn = blockIdx.x >> 5;             // 0..23
  int m0 = bm * 128, n0 = bn * 128;
  int tid = threadIdx.x, lane = tid & 63, w = tid >> 6;
  int g = lane >> 4, l15 = lane & 15;
  int wr = w >> 1, wc = w & 1;

  __shared__ u16 Alds[2][128 * 32];     // 8KB per buf
  __shared__ u16 Blds[2][128 * 32];

  f32x4 acc[4][4] = {};

  int rowW = w * 16 + (lane >> 2);
  int cSrc = (lane & 3) ^ ((lane >> 3) & 3);
  const u16* Ag0 = A  + (size_t)(m0 + rowW) * K + cSrc * 8;
  const u16* Ag1 = A  + (size_t)(m0 + 64 + rowW) * K + cSrc * 8;
  const u16* Bg0 = BT + (size_t)(n0 + rowW) * K + cSrc * 8;
  const u16* Bg1 = BT + (size_t)(n0 + 64 + rowW) * K + cSrc * 8;

  auto stage = [&](int k0, int buf) {
    gload16(Ag0 + k0, (char*)&Alds[buf][0] + w * 1024);
    gload16(Ag1 + k0, (char*)&Alds[buf][0] + 4096 + w * 1024);
    gload16(Bg0 + k0, (char*)&Blds[buf][0] + w * 1024);
    gload16(Bg1 + k0, (char*)&Blds[buf][0] + 4096 + w * 1024);
  };

  stage(0, 0);
  __syncthreads();
  int cur = 0;

#pragma unroll 1
  for (int it = 0; it < 32; ++it) {
    if (it + 1 < 32) stage((it + 1) * 32, cur ^ 1);  // loads fly under compute
    const char* Ab = (const char*)&Alds[cur][0];
    const char* Bb = (const char*)&Blds[cur][0];
    bf16x8 af[4], bf_[4];
#pragma unroll
    for (int m = 0; m < 4; ++m) {
      int r = wr * 64 + m * 16 + l15;
      af[m] = *(const bf16x8*)(Ab + r * 64 + ((g ^ ((r >> 1) & 3)) << 4));
    }
#pragma unroll
    for (int n = 0; n < 4; ++n) {
      int r = wc * 64 + n * 16 + l15;
      bf_[n] = *(const bf16x8*)(Bb + r * 64 + ((g ^ ((r >> 1) & 3)) << 4));
    }
#pragma unroll
    for (int m = 0; m < 4; ++m)
#pragma unroll
      for (int n = 0; n < 4; ++n)
        acc[m][n] = mfma16(af[m], bf_[n], acc[m][n]);
    __syncthreads();                    // single barrier: drains loads + reads
    cur ^= 1;
  }

  int bq = m0 >> 11;                    // batch index (uniform per tile)

  if (bn >= 16) {
    // ---- V: transposed store into VT[bh][d][t], 4 tokens packed per store
#pragma unroll
    for (int m = 0; m < 4; ++m) {
      int rowb = m0 + wr * 64 + m * 16 + 4 * g;
      int tt = rowb & 2047;
#pragma unroll
      for (int n = 0; n < 4; ++n) {
        int colv = n0 + wc * 64 + n * 16 + l15 - 2048;
        float bv = bias[colv + 2048];
        int h = colv >> 6, d = colv & 63;
        int bh = bq * 16 + h;
        u32x2 o = { pk2(acc[m][n][0] + bv, acc[m][n][1] + bv),
                    pk2(acc[m][n][2] + bv, acc[m][n][3] + bv) };
        *(u32x2*)(VT + ((size_t)(bh * 64 + d)) * 2048 + tt) = o;
      }
    }
  } else {
    // ---- Q/K: fused RoPE via __shfl_xor(v,1) partner exchange
    bool isQ = (bn < 8);
    u16* OUT = isQ ? QR : KR;
    int cofs = isQ ? 0 : 1024;
    float sc = isQ ? 0.125f : 1.0f;
#pragma unroll
    for (int m = 0; m < 4; ++m) {
      int rowb = m0 + wr * 64 + m * 16 + 4 * g;
#pragma unroll
      for (int n = 0; n < 4; ++n) {
        int col = n0 + wc * 64 + n * 16 + l15 - cofs;
        float bv = bias[col + cofs];
        int h = col >> 6, f = col & 63;
        int bh = bq * 16 + h;
        int dp = f >> 1;
        int outf = (f & 1) ? (32 + dp) : dp;
#pragma unroll
        for (int j = 0; j < 4; ++j) {
          int tt = (rowb + j) & 2047;
          float v = acc[m][n][j] + bv;
          float pv = __shfl_xor(v, 1);
          float sn = sint[tt * 32 + dp], cs = cost[tt * 32 + dp];
          float out = (f & 1) ? (pv * sn + v * cs) : (v * cs - pv * sn);
          OUT[((size_t)(bh * 2048 + tt)) * 64 + outf] = f2bf(sc * out);
        }
      }
    }
  }
}

// ---- proj GEMM v2: 64x128 tiles, 2 waves, 2 blocks/CU ----------------------
// R15 finding: proj's 256-block grid = 1 block/CU -> every barrier couples all
// waves with no co-tenant to hide the drain. 64x128 tiles -> 512 blocks x 128
// thr = 2 blocks/CU: co-resident block's waves fill each other's stalls
// (m114 mechanism). Row stride 64B, XOR chunk^((row>>1)&3) on global source
// (<=2-way bank aliasing = free, m136), same single-barrier m97 loop.
__global__ __launch_bounds__(128) void k_gemm_proj(const u16* __restrict__ A,
                                                   const u16* __restrict__ BT,
                                                   const float* __restrict__ bias,
                                                   float* __restrict__ Cout) {
  constexpr int K = 1024, N = 1024;
  int bm = blockIdx.x >> 3;           // 0..63
  int bn = blockIdx.x & 7;            // 0..7 (consecutive blocks share A-panel)
  int m0 = bm * 64, n0 = bn * 128;
  int tid = threadIdx.x, lane = tid & 63, w = tid >> 6;  // w in {0,1}
  int g = lane >> 4, l15 = lane & 15;

  __shared__ u16 Alds[2][64 * 32];    // 4KB per buf
  __shared__ u16 Blds[2][128 * 32];   // 8KB per buf

  f32x4 acc[4][4] = {};

  // staging: slot = i*128 + tid; row = i*32 + (tid>>2); c = tid&3
  int rT = tid >> 2;                  // 0..31
  int cT = tid & 3;
  const u16* AgBase = A  + (size_t)m0 * K;
  const u16* BgBase = BT + (size_t)n0 * K;

  auto stage = [&](int k0, int buf) {
#pragma unroll
    for (int i = 0; i < 2; ++i) {     // A: 64 rows x 4 chunks
      int row = i * 32 + rT;
      int csrc = cT ^ ((row >> 1) & 3);
      gload16(AgBase + (size_t)row * K + k0 + csrc * 8,
              (char*)&Alds[buf][0] + i * 2048 + w * 1024);
    }
#pragma unroll
    for (int i = 0; i < 4; ++i) {     // B: 128 rows x 4 chunks
      int row = i * 32 + rT;
      int csrc = cT ^ ((row >> 1) & 3);
      gload16(BgBase + (size_t)row * K + k0 + csrc * 8,
              (char*)&Blds[buf][0] + i * 2048 + w * 1024);
    }
  };

  stage(0, 0);
  __syncthreads();
  int cur = 0;

#pragma unroll 1
  for (int it = 0; it < 32; ++it) {
    if (it + 1 < 32) stage((it + 1) * 32, cur ^ 1);
    const char* Ab = (const char*)&Alds[cur][0];
    const char* Bb = (const char*)&Blds[cur][0];
    bf16x8 af[4], bf_[4];
#pragma unroll
    for (int m = 0; m < 4; ++m) {
      int r = m * 16 + l15;
      af[m] = *(const bf16x8*)(Ab + r * 64 + ((g ^ ((r >> 1) & 3)) << 4));
    }
#pragma unroll
    for (int n = 0; n < 4; ++n) {
      int r = w * 64 + n * 16 + l15;
      bf_[n] = *(const bf16x8*)(Bb + r * 64 + ((g ^ ((r >> 1) & 3)) << 4));
    }
#pragma unroll
    for (int m = 0; m < 4; ++m)
#pragma unroll
      for (int n = 0; n < 4; ++n)
        acc[m][n] = mfma16(af[m], bf_[n], acc[m][n]);
    __syncthreads();
    cur ^= 1;
  }

#pragma unroll
  for (int m = 0; m < 4; ++m) {
    int rowb = m0 + m * 16 + 4 * g;
#pragma unroll
    for (int n = 0; n < 4; ++n) {
      int col = n0 + w * 64 + n * 16 + l15;
      float bv = bias[col];
#pragma unroll
      for (int j = 0; j < 4; ++j)
        Cout[(size_t)(rowb + j) * N + col] = acc[m][n][j] + bv;
    }
  }
}

// ---- causal flash attention (R5/R13 verbatim — proven 46 us) ---------------
__global__ __launch_bounds__(256, 4) void k_attn(const u16* __restrict__ QR,
                                                 const u16* __restrict__ KR,
                                                 const u16* __restrict__ VT,
                                                 u16* __restrict__ AO) {
  int tid = threadIdx.x;
  int w = tid >> 6, lane = tid & 63;
  int g = lane >> 4, l15 = lane & 15;
  int l7 = l15 & 7, g2 = g >> 1;

  int idx = blockIdx.x;
  int tt = 31 - (idx >> 5);          // q-tile 31..0 (heavy first)
  int bh = idx & 31;                 // bh mod 8 = XCD slot -> 4 bh per XCD
  int nt = tt + 1;                   // 64-key tiles to process
  int b = bh >> 4, h = bh & 15;
  int q0 = tt * 64 + w * 16;         // wave's 16-row subtile
  int qa = q0 + l15;

  const u16* Kg = KR + (size_t)bh * 2048 * 64;
  const u16* Vg = VT + (size_t)bh * 64 * 2048;

  __shared__ u16 Klds[2][64 * 64];   // 8KB/buf: [key][64 d], swizzled
  __shared__ u16 Vlds[2][64 * 64];   // 8KB/buf: [d][64 key], swizzled

  const u16* Qr = QR + ((size_t)bh * 2048 + q0 + l15) * 64 + 8 * g;
  bf16x8 qf0 = *(const bf16x8*)(Qr);
  bf16x8 qf1 = *(const bf16x8*)(Qr + 32);

  f32x4 o[4] = {};
  float m = -1e30f, l = 0.f;

  // hoisted LDS read constants
  int kx0 = ((g ^ l7) << 4);                 // K frag chunk offsets (bytes)
  int kx1 = (((4 + g) ^ l7) << 4);
  int vx0 = ((g2 ^ l7) << 4);                // V chunks s2=0: {g2, 2+g2}
  int vx1 = (((2 + g2) ^ l7) << 4);
  int vx2 = (((4 + g2) ^ l7) << 4);          // s2=1: {4+g2, 6+g2}
  int vx3 = (((6 + g2) ^ l7) << 4);
  int vbase = l15 * 128 + ((g & 1) << 3);

  // staging: 256 threads cover 64 rows x 8 chunks in 2 issues (K and V each)
  int rstg = lane >> 3;                      // 0..7
  int cswz = (lane & 7) ^ rstg;              // pre-swizzled source chunk

  auto stage = [&](int kt, int buf) {
#pragma unroll
    for (int j = 0; j < 2; ++j) {
      int r = j * 32 + w * 8 + rstg;
      gload16(Kg + (size_t)(kt * 64 + r) * 64 + cswz * 8,
              &Klds[buf][(j * 32 + w * 8) * 64]);
      gload16(Vg + (size_t)r * 2048 + kt * 64 + cswz * 8,
              &Vlds[buf][(j * 32 + w * 8) * 64]);
    }
  };

  stage(0, 0);
  __syncthreads();
  int cur = 0;

  for (int t = 0; t < nt; ++t) {
    if (t + 1 < nt) stage(t + 1, cur ^ 1);   // async prefetch next tile
    const char* Kb = (const char*)&Klds[cur][0];
    const char* Vb = (const char*)&Vlds[cur][0];

    // S^T = K.Q (64 keys x 16 q)
    f32x4 sb[4];
    __builtin_amdgcn_s_setprio(1);
#pragma unroll
    for (int blk = 0; blk < 4; ++blk) {
      const char* kb = Kb + blk * 2048 + l15 * 128;
      bf16x8 k0 = *(const bf16x8*)(kb + kx0);
      bf16x8 k1 = *(const bf16x8*)(kb + kx1);
      f32x4 z = { 0.f, 0.f, 0.f, 0.f };
      z = mfma16(k0, qf0, z);
      sb[blk] = mfma16(k1, qf1, z);
    }
    __builtin_amdgcn_s_setprio(0);

    if (t == nt - 1) {               // causal mask, final tile only
      int tk0 = t * 64;
#pragma unroll
      for (int blk = 0; blk < 4; ++blk)
#pragma unroll
        for (int j = 0; j < 4; ++j) {
          int tk = tk0 + blk * 16 + 4 * g + j;
          if (tk > qa) sb[blk][j] = -1e30f;
        }
    }

    // online softmax (defer-max) + PV
    float mx = fmaxf(fmaxf(fmaxf(sb[0][0], sb[0][1]), fmaxf(sb[0][2], sb[0][3])),
                     fmaxf(fmaxf(sb[1][0], sb[1][1]), fmaxf(sb[1][2], sb[1][3])));
    mx = fmaxf(mx, fmaxf(fmaxf(fmaxf(sb[2][0], sb[2][1]), fmaxf(sb[2][2], sb[2][3])),
                         fmaxf(fmaxf(sb[3][0], sb[3][1]), fmaxf(sb[3][2], sb[3][3]))));
    mx = fmaxf(mx, __shfl_xor(mx, 16));
    mx = fmaxf(mx, __shfl_xor(mx, 32));
    if (!__all(mx <= m + 8.0f)) {
      float mnew = fmaxf(m, mx);
      float a = __builtin_amdgcn_exp2f((m - mnew) * 1.44269504f);
      l *= a;
#pragma unroll
      for (int d = 0; d < 4; ++d) o[d] *= a;
      m = mnew;
    }
    float em = m * 1.44269504f;
    float p[4][4];
    float ps = 0.f;
#pragma unroll
    for (int blk = 0; blk < 4; ++blk)
#pragma unroll
      for (int j = 0; j < 4; ++j) {
        float pv = __builtin_amdgcn_exp2f(__builtin_fmaf(sb[blk][j], 1.44269504f, -em));
        p[blk][j] = pv;
        ps += pv;
      }
    l += ps;

    __builtin_amdgcn_s_setprio(1);
#pragma unroll
    for (int s2 = 0; s2 < 2; ++s2) {
      u32x4 pw = { cvtpk(p[2 * s2][0], p[2 * s2][1]),
                   cvtpk(p[2 * s2][2], p[2 * s2][3]),
                   cvtpk(p[2 * s2 + 1][0], p[2 * s2 + 1][1]),
                   cvtpk(p[2 * s2 + 1][2], p[2 * s2 + 1][3]) };
      bf16x8 pb = __builtin_bit_cast(bf16x8, pw);
      int cl = s2 ? vx2 : vx0;
      int ch = s2 ? vx3 : vx1;
#pragma unroll
      for (int dblk = 0; dblk < 4; ++dblk) {
        uint2 lo = *(const uint2*)(Vb + vbase + dblk * 2048 + cl);
        uint2 hi = *(const uint2*)(Vb + vbase + dblk * 2048 + ch);
        bf16x8 va = __builtin_bit_cast(bf16x8, u32x4{ lo.x, lo.y, hi.x, hi.y });
        o[dblk] = mfma16(va, pb, o[dblk]);
      }
    }
    __builtin_amdgcn_s_setprio(0);

    __syncthreads();
    cur ^= 1;
  }

  float lt = l + __shfl_xor(l, 16);
  lt += __shfl_xor(lt, 32);
  float inv = 1.0f / lt;
  u16* orow = AO + ((size_t)b * 2048 + q0 + l15) * 1024 + h * 64 + 4 * g;
#pragma unroll
  for (int dblk = 0; dblk < 4; ++dblk) {
    u32x2 ov = { cvtpk(o[dblk][0] * inv, o[dblk][1] * inv),
                 cvtpk(o[dblk][2] * inv, o[dblk][3] * inv) };
    *(u32x2*)(orow + dblk * 16) = ov;
  }
}

// ---- launcher ---------------------------------------------------------------
extern "C" void kernel_launch(void* const* d_in, const int* in_sizes, int n_in,
                              void* d_out, int out_size, void* d_ws, size_t ws_size,
                              hipStream_t stream) {
  (void)in_sizes; (void)n_in; (void)out_size; (void)ws_size;
  const float* x     = (const float*)d_in[0];
  const float* Wqkv  = (const float*)d_in[1];
  const float* bqkv  = (const float*)d_in[2];
  const float* Wproj = (const float*)d_in[3];
  const float* bproj = (const float*)d_in[4];
  const int*   pos   = (const int*)d_in[5];

  char* ws = (char*)d_ws;
  u16*   XB     = (u16*)(ws + 0);
  u16*   WQKVT  = (u16*)(ws + 8388608);
  u16*   WPROJT = (u16*)(ws + 14680064);
  u16*   QR     = (u16*)(ws + 41943040);
  u16*   KR     = (u16*)(ws + 50331648);
  u16*   VT     = (u16*)(ws + 58720256);
  u16*   AO     = (u16*)(ws + 67108864);
  float* SIN    = (float*)(ws + 75497472);
  float* COS    = (float*)(ws + 75759616);

  k_prep<<<6400, 256, 0, stream>>>(x, XB, Wqkv, WQKVT, Wproj, WPROJT, pos, SIN, COS);
  k_gemm_qkv<<<32 * 24, 256, 0, stream>>>(XB, WQKVT, bqkv, QR, KR, VT, SIN, COS);
  k_attn<<<1024, 256, 0, stream>>>(QR, KR, VT, AO);
  k_gemm_proj<<<512, 128, 0, stream>>>(AO, WPROJT, bproj, (float*)d_out);
}

// Round 18
// 111.336 us; speedup vs baseline: 1.0804x; 1.0163x over previous
//
#include <hip/hip_runtime.h>
#include <hip/hip_bf16.h>
#include <stdint.h>

#define DEV __device__ __forceinline__

typedef unsigned short u16;
typedef unsigned int   u32;
typedef __attribute__((ext_vector_type(8))) short bf16x8;   // 8 bf16 = 4 VGPRs
typedef __attribute__((ext_vector_type(4))) float f32x4;
typedef __attribute__((ext_vector_type(4))) u32   u32x4;
typedef __attribute__((ext_vector_type(2))) u32   u32x2;

// ---- numeric helpers -------------------------------------------------------
DEV u16 f2bf(float f) {            // RNE f32 -> bf16
  u32 u = __builtin_bit_cast(u32, f);
  u = (u + 0x7fffu + ((u >> 16) & 1u)) >> 16;
  return (u16)u;
}
DEV float bf2f(u16 h) { return __builtin_bit_cast(float, (u32)h << 16); }
DEV u32 pk2(float a, float b) {    // pack 2 f32 -> 2 bf16 in one u32 (RNE)
  u32 x = __builtin_bit_cast(u32, a), y = __builtin_bit_cast(u32, b);
  x = (x + 0x7fffu + ((x >> 16) & 1u)) >> 16;
  y = (y + 0x7fffu + ((y >> 16) & 1u)) >> 16;
  return x | (y << 16);
}
DEV u32 cvtpk(float lo, float hi) {  // 1-instr RNE pack (same semantics as pk2)
  u32 r;
  asm("v_cvt_pk_bf16_f32 %0, %1, %2" : "=v"(r) : "v"(lo), "v"(hi));
  return r;
}
DEV f32x4 mfma16(bf16x8 a, bf16x8 b, f32x4 c) {
  return __builtin_amdgcn_mfma_f32_16x16x32_bf16(a, b, c, 0, 0, 0);
}
DEV void gload16(const void* g, void* l) {   // global -> LDS direct, 16B/lane
  __builtin_amdgcn_global_load_lds(
      (const __attribute__((address_space(1))) void*)g,
      (__attribute__((address_space(3))) void*)l, 16, 0, 0);
}

// ---- problem constants -----------------------------------------------------
// B=2 T=2048 DIM=1024 HEADS=16 HEAD_DIM=64; tokens = 4096
// workspace layout (bytes):
//  XB      0         x as bf16            [4096][1024]
//  WQKVT   8388608   Wqkv^T bf16          [3072][1024]
//  WPROJT  14680064  Wproj^T bf16         [1024][1024]
//  QR      41943040  roped*scale Q bf16   [32][2048][64]
//  KR      50331648  roped K bf16         [32][2048][64]
//  VT      58720256  V^T bf16             [32][64][2048]
//  AO      67108864  attn out bf16        [4096][1024]
//  SIN     75497472  f32 [2048][32]
//  COS     75759616  f32 [2048][32]

// ---- merged prep kernel ----------------------------------------------------
__global__ __launch_bounds__(256) void k_prep(const float* __restrict__ x,
                                              u16* __restrict__ XB,
                                              const float* __restrict__ Wqkv,
                                              u16* __restrict__ WQKVT,
                                              const float* __restrict__ Wproj,
                                              u16* __restrict__ WPROJT,
                                              const int* __restrict__ posp,
                                              float* __restrict__ sint,
                                              float* __restrict__ cost) {
  __shared__ float t[32][33];
  int bid = blockIdx.x;
  int tid = threadIdx.x;

  if (bid < 2048) {                        // ---- cvt x -> bf16
    size_t i = ((size_t)bid * 256 + tid) * 8;
    float4 a = *(const float4*)(x + i);
    float4 b = *(const float4*)(x + i + 4);
    u32x4 o = { pk2(a.x, a.y), pk2(a.z, a.w), pk2(b.x, b.y), pk2(b.z, b.w) };
    *(u32x4*)(XB + i) = o;
    return;
  }
  if (bid < 6144) {                        // ---- W transpose+cvt
    const float* W; u16* WT; int Ndim, idx;
    if (bid < 5120) { W = Wqkv;  WT = WQKVT;  Ndim = 3072; idx = bid - 2048; }
    else            { W = Wproj; WT = WPROJT; Ndim = 1024; idx = bid - 5120; }
    int bk = idx & 31;
    int bn = idx >> 5;
    int k0 = bk * 32, n0 = bn * 32;
    int tx = tid & 31, ty = tid >> 5;      // ty 0..7
#pragma unroll
    for (int i = 0; i < 4; ++i)
      t[ty + 8 * i][tx] = W[(size_t)(k0 + ty + 8 * i) * Ndim + n0 + tx];
    __syncthreads();
#pragma unroll
    for (int i = 0; i < 4; ++i) {
      int n = ty + 8 * i;
      WT[(size_t)(n0 + n) * 1024 + k0 + tx] = f2bf(t[tx][n]);
    }
    return;
  }
  // ---- rope tables
  int i = (bid - 6144) * 256 + tid;        // 65536 = 2048*32
  int tt = i >> 5, d = i & 31;
  float theta = exp2f(-(float)d * (13.2877123795494f / 32.0f));
  float ang = (float)(posp[0] + tt) * theta;
  sint[i] = sinf(ang);
  cost[i] = cosf(ang);
}

// ---- QKV GEMM, fused RoPE/V-transpose, LDS-coalesced epilogue --------------
// Main loop = R13's m97 single-barrier structure (unchanged). Epilogue:
// phase 1 writes roped Q/K (or packed V quads) into the dead 32KB A/B LDS
// reused as a 128x128 bf16 staging tile (scattered LDS writes, XOR-granule
// swizzle gr^=row&7 for <=4-way banks); phase 2 reads rows back as bf16x8 and
// issues 8x16B fully-coalesced global stores/thread — replaces R13's 64x2B
// scattered global stores. (R17 compile fix: LDS buffer addrs computed
// inline, no pointer arrays of __shared__.)
__global__ __launch_bounds__(256, 3) void k_gemm_qkv(const u16* __restrict__ A,
                                                     const u16* __restrict__ BT,
                                                     const float* __restrict__ bias,
                                                     u16* __restrict__ QR,
                                                     u16* __restrict__ KR,
                                                     u16* __restrict__ VT,
                                                     const float* __restrict__ sint,
                                                     const float* __restrict__ cost) {
  constexpr int K = 1024;
  int bm = blockIdx.x & 31;             // M/128 = 32
  int bn = blockIdx.x >> 5;             // 0..23
  int m0 = bm * 128, n0 = bn * 128;
  int tid = threadIdx.x, lane = tid & 63, w = tid >> 6;
  int g = lane >> 4, l15 = lane & 15;
  int wr = w >> 1, wc = w & 1;

  __shared__ u16 smem[16384];           // 32KB: A dbuf | B dbuf, reused as stg

  f32x4 acc[4][4] = {};

  int rowW = w * 16 + (lane >> 2);
  int cSrc = (lane & 3) ^ ((lane >> 3) & 3);
  const u16* Ag0 = A  + (size_t)(m0 + rowW) * K + cSrc * 8;
  const u16* Ag1 = A  + (size_t)(m0 + 64 + rowW) * K + cSrc * 8;
  const u16* Bg0 = BT + (size_t)(n0 + rowW) * K + cSrc * 8;
  const u16* Bg1 = BT + (size_t)(n0 + 64 + rowW) * K + cSrc * 8;

  auto stage = [&](int k0, int buf) {
    char* Ab = (char*)(smem + buf * 4096);
    char* Bb = (char*)(smem + 8192 + buf * 4096);
    gload16(Ag0 + k0, Ab + w * 1024);
    gload16(Ag1 + k0, Ab + 4096 + w * 1024);
    gload16(Bg0 + k0, Bb + w * 1024);
    gload16(Bg1 + k0, Bb + 4096 + w * 1024);
  };

  stage(0, 0);
  __syncthreads();
  int cur = 0;

#pragma unroll 1
  for (int it = 0; it < 32; ++it) {
    if (it + 1 < 32) stage((it + 1) * 32, cur ^ 1);  // loads fly under compute
    const char* Ab = (const char*)(smem + cur * 4096);
    const char* Bb = (const char*)(smem + 8192 + cur * 4096);
    bf16x8 af[4], bf_[4];
#pragma unroll
    for (int m = 0; m < 4; ++m) {
      int r = wr * 64 + m * 16 + l15;
      af[m] = *(const bf16x8*)(Ab + r * 64 + ((g ^ ((r >> 1) & 3)) << 4));
    }
#pragma unroll
    for (int n = 0; n < 4; ++n) {
      int r = wc * 64 + n * 16 + l15;
      bf_[n] = *(const bf16x8*)(Bb + r * 64 + ((g ^ ((r >> 1) & 3)) << 4));
    }
#pragma unroll
    for (int m = 0; m < 4; ++m)
#pragma unroll
      for (int n = 0; n < 4; ++n)
        acc[m][n] = mfma16(af[m], bf_[n], acc[m][n]);
    __syncthreads();                    // single barrier: drains loads + reads
    cur ^= 1;
  }
  // K-loop done; last __syncthreads guarantees all LDS reads complete.
  // smem is now dead -> reuse as 128x128 bf16 staging tile.
  int bq = m0 >> 11;                    // batch index (uniform per tile)

  if (bn >= 16) {
    // ---- V phase 1: packed token-quads into stg[h*64+d][t_local] (swizzled)
#pragma unroll
    for (int m = 0; m < 4; ++m) {
      int tl = wr * 64 + m * 16 + 4 * g;          // t_local, multiple of 4
#pragma unroll
      for (int n = 0; n < 4; ++n) {
        int colv = n0 + wc * 64 + n * 16 + l15 - 2048;
        float bv = bias[colv + 2048];
        int row = ((colv >> 6) & 1) * 64 + (colv & 63);  // h_local*64 + d
        int gr = ((tl >> 3) ^ (row & 7)) << 3;           // swizzled granule
        u32x2 o = { pk2(acc[m][n][0] + bv, acc[m][n][1] + bv),
                    pk2(acc[m][n][2] + bv, acc[m][n][3] + bv) };
        *(u32x2*)&smem[row * 128 + gr + (tl & 7)] = o;
      }
    }
  } else {
    // ---- Q/K phase 1: roped values into stg[t_local][h_local*64+outf]
    bool isQ = (bn < 8);
    int cofs = isQ ? 0 : 1024;
    float sc = isQ ? 0.125f : 1.0f;
#pragma unroll
    for (int m = 0; m < 4; ++m) {
      int rowb = m0 + wr * 64 + m * 16 + 4 * g;
#pragma unroll
      for (int n = 0; n < 4; ++n) {
        int col = n0 + wc * 64 + n * 16 + l15 - cofs;
        float bv = bias[col + cofs];
        int f = col & 63;
        int hl = (col >> 6) & 1;
        int dp = f >> 1;
        int outf = (f & 1) ? (32 + dp) : dp;
        int cq = hl * 64 + outf;                  // natural col 0..127
#pragma unroll
        for (int j = 0; j < 4; ++j) {
          int row = (rowb + j) & 127;             // t_local
          float v = acc[m][n][j] + bv;
          float pv = __shfl_xor(v, 1);
          float sn = sint[((rowb + j) & 2047) * 32 + dp];
          float cs = cost[((rowb + j) & 2047) * 32 + dp];
          float out = (f & 1) ? (pv * sn + v * cs) : (v * cs - pv * sn);
          int gr = ((cq >> 3) ^ (row & 7)) << 3;  // swizzled granule
          smem[row * 128 + gr + (cq & 7)] = f2bf(sc * out);
        }
      }
    }
  }
  __syncthreads();

  // ---- phase 2: coalesced read-out. 128 rows x 16 granules of 16B.
  // Q/K: row = t_local, col = h_local*64 + outf -> OUT[(bh*2048+t)*64+...]
  // V:   row = h_local*64 + d, col = t_local    -> VT[(bh*64+d)*2048+t0+...]
#pragma unroll
  for (int i = 0; i < 8; ++i) {
    int slot = i * 256 + tid;
    int row = slot >> 4;                          // 0..127
    int ch = slot & 15;                           // natural granule
    bf16x8 val = *(const bf16x8*)&smem[row * 128 + ((ch ^ (row & 7)) << 3)];
    if (bn >= 16) {
      int hl = row >> 6, d = row & 63;
      int bh = bq * 16 + (bn - 16) * 2 + hl;
      int t0 = m0 & 2047;
      *(bf16x8*)(VT + ((size_t)bh * 64 + d) * 2048 + t0 + ch * 8) = val;
    } else {
      bool isQ = (bn < 8);
      int hl = ch >> 3, cc = ch & 7;
      int bh = bq * 16 + (isQ ? bn * 2 : (bn - 8) * 2) + hl;
      int tt = (m0 + row) & 2047;
      u16* OUT = isQ ? QR : KR;
      *(bf16x8*)(OUT + ((size_t)bh * 2048 + tt) * 64 + cc * 8) = val;
    }
  }
}

// ---- proj GEMM v2: 64x128 tiles, 2 waves, 2 blocks/CU (R16, unchanged) -----
__global__ __launch_bounds__(128) void k_gemm_proj(const u16* __restrict__ A,
                                                   const u16* __restrict__ BT,
                                                   const float* __restrict__ bias,
                                                   float* __restrict__ Cout) {
  constexpr int K = 1024, N = 1024;
  int bm = blockIdx.x >> 3;           // 0..63
  int bn = blockIdx.x & 7;            // 0..7
  int m0 = bm * 64, n0 = bn * 128;
  int tid = threadIdx.x, lane = tid & 63, w = tid >> 6;  // w in {0,1}
  int g = lane >> 4, l15 = lane & 15;

  __shared__ u16 Alds[2][64 * 32];    // 4KB per buf
  __shared__ u16 Blds[2][128 * 32];   // 8KB per buf

  f32x4 acc[4][4] = {};

  int rT = tid >> 2;                  // 0..31
  int cT = tid & 3;
  const u16* AgBase = A  + (size_t)m0 * K;
  const u16* BgBase = BT + (size_t)n0 * K;

  auto stage = [&](int k0, int buf) {
#pragma unroll
    for (int i = 0; i < 2; ++i) {     // A: 64 rows x 4 chunks
      int row = i * 32 + rT;
      int csrc = cT ^ ((row >> 1) & 3);
      gload16(AgBase + (size_t)row * K + k0 + csrc * 8,
              (char*)&Alds[buf][0] + i * 2048 + w * 1024);
    }
#pragma unroll
    for (int i = 0; i < 4; ++i) {     // B: 128 rows x 4 chunks
      int row = i * 32 + rT;
      int csrc = cT ^ ((row >> 1) & 3);
      gload16(BgBase + (size_t)row * K + k0 + csrc * 8,
              (char*)&Blds[buf][0] + i * 2048 + w * 1024);
    }
  };

  stage(0, 0);
  __syncthreads();
  int cur = 0;

#pragma unroll 1
  for (int it = 0; it < 32; ++it) {
    if (it + 1 < 32) stage((it + 1) * 32, cur ^ 1);
    const char* Ab = (const char*)&Alds[cur][0];
    const char* Bb = (const char*)&Blds[cur][0];
    bf16x8 af[4], bf_[4];
#pragma unroll
    for (int m = 0; m < 4; ++m) {
      int r = m * 16 + l15;
      af[m] = *(const bf16x8*)(Ab + r * 64 + ((g ^ ((r >> 1) & 3)) << 4));
    }
#pragma unroll
    for (int n = 0; n < 4; ++n) {
      int r = w * 64 + n * 16 + l15;
      bf_[n] = *(const bf16x8*)(Bb + r * 64 + ((g ^ ((r >> 1) & 3)) << 4));
    }
#pragma unroll
    for (int m = 0; m < 4; ++m)
#pragma unroll
      for (int n = 0; n < 4; ++n)
        acc[m][n] = mfma16(af[m], bf_[n], acc[m][n]);
    __syncthreads();
    cur ^= 1;
  }

#pragma unroll
  for (int m = 0; m < 4; ++m) {
    int rowb = m0 + m * 16 + 4 * g;
#pragma unroll
    for (int n = 0; n < 4; ++n) {
      int col = n0 + w * 64 + n * 16 + l15;
      float bv = bias[col];
#pragma unroll
      for (int j = 0; j < 4; ++j)
        Cout[(size_t)(rowb + j) * N + col] = acc[m][n][j] + bv;
    }
  }
}

// ---- causal flash attention (R5/R13 verbatim — proven 46 us) ---------------
__global__ __launch_bounds__(256, 4) void k_attn(const u16* __restrict__ QR,
                                                 const u16* __restrict__ KR,
                                                 const u16* __restrict__ VT,
                                                 u16* __restrict__ AO) {
  int tid = threadIdx.x;
  int w = tid >> 6, lane = tid & 63;
  int g = lane >> 4, l15 = lane & 15;
  int l7 = l15 & 7, g2 = g >> 1;

  int idx = blockIdx.x;
  int tt = 31 - (idx >> 5);          // q-tile 31..0 (heavy first)
  int bh = idx & 31;                 // bh mod 8 = XCD slot -> 4 bh per XCD
  int nt = tt + 1;                   // 64-key tiles to process
  int b = bh >> 4, h = bh & 15;
  int q0 = tt * 64 + w * 16;         // wave's 16-row subtile
  int qa = q0 + l15;

  const u16* Kg = KR + (size_t)bh * 2048 * 64;
  const u16* Vg = VT + (size_t)bh * 64 * 2048;

  __shared__ u16 Klds[2][64 * 64];   // 8KB/buf: [key][64 d], swizzled
  __shared__ u16 Vlds[2][64 * 64];   // 8KB/buf: [d][64 key], swizzled

  const u16* Qr = QR + ((size_t)bh * 2048 + q0 + l15) * 64 + 8 * g;
  bf16x8 qf0 = *(const bf16x8*)(Qr);
  bf16x8 qf1 = *(const bf16x8*)(Qr + 32);

  f32x4 o[4] = {};
  float m = -1e30f, l = 0.f;

  // hoisted LDS read constants
  int kx0 = ((g ^ l7) << 4);                 // K frag chunk offsets (bytes)
  int kx1 = (((4 + g) ^ l7) << 4);
  int vx0 = ((g2 ^ l7) << 4);                // V chunks s2=0: {g2, 2+g2}
  int vx1 = (((2 + g2) ^ l7) << 4);
  int vx2 = (((4 + g2) ^ l7) << 4);          // s2=1: {4+g2, 6+g2}
  int vx3 = (((6 + g2) ^ l7) << 4);
  int vbase = l15 * 128 + ((g & 1) << 3);

  // staging: 256 threads cover 64 rows x 8 chunks in 2 issues (K and V each)
  int rstg = lane >> 3;                      // 0..7
  int cswz = (lane & 7) ^ rstg;              // pre-swizzled source chunk

  auto stage = [&](int kt, int buf) {
#pragma unroll
    for (int j = 0; j < 2; ++j) {
      int r = j * 32 + w * 8 + rstg;
      gload16(Kg + (size_t)(kt * 64 + r) * 64 + cswz * 8,
              &Klds[buf][(j * 32 + w * 8) * 64]);
      gload16(Vg + (size_t)r * 2048 + kt * 64 + cswz * 8,
              &Vlds[buf][(j * 32 + w * 8) * 64]);
    }
  };

  stage(0, 0);
  __syncthreads();
  int cur = 0;

  for (int t = 0; t < nt; ++t) {
    if (t + 1 < nt) stage(t + 1, cur ^ 1);   // async prefetch next tile
    const char* Kb = (const char*)&Klds[cur][0];
    const char* Vb = (const char*)&Vlds[cur][0];

    // S^T = K.Q (64 keys x 16 q)
    f32x4 sb[4];
    __builtin_amdgcn_s_setprio(1);
#pragma unroll
    for (int blk = 0; blk < 4; ++blk) {
      const char* kb = Kb + blk * 2048 + l15 * 128;
      bf16x8 k0 = *(const bf16x8*)(kb + kx0);
      bf16x8 k1 = *(const bf16x8*)(kb + kx1);
      f32x4 z = { 0.f, 0.f, 0.f, 0.f };
      z = mfma16(k0, qf0, z);
      sb[blk] = mfma16(k1, qf1, z);
    }
    __builtin_amdgcn_s_setprio(0);

    if (t == nt - 1) {               // causal mask, final tile only
      int tk0 = t * 64;
#pragma unroll
      for (int blk = 0; blk < 4; ++blk)
#pragma unroll
        for (int j = 0; j < 4; ++j) {
          int tk = tk0 + blk * 16 + 4 * g + j;
          if (tk > qa) sb[blk][j] = -1e30f;
        }
    }

    // online softmax (defer-max) + PV
    float mx = fmaxf(fmaxf(fmaxf(sb[0][0], sb[0][1]), fmaxf(sb[0][2], sb[0][3])),
                     fmaxf(fmaxf(sb[1][0], sb[1][1]), fmaxf(sb[1][2], sb[1][3])));
    mx = fmaxf(mx, fmaxf(fmaxf(fmaxf(sb[2][0], sb[2][1]), fmaxf(sb[2][2], sb[2][3])),
                         fmaxf(fmaxf(sb[3][0], sb[3][1]), fmaxf(sb[3][2], sb[3][3]))));
    mx = fmaxf(mx, __shfl_xor(mx, 16));
    mx = fmaxf(mx, __shfl_xor(mx, 32));
    if (!__all(mx <= m + 8.0f)) {
      float mnew = fmaxf(m, mx);
      float a = __builtin_amdgcn_exp2f((m - mnew) * 1.44269504f);
      l *= a;
#pragma unroll
      for (int d = 0; d < 4; ++d) o[d] *= a;
      m = mnew;
    }
    float em = m * 1.44269504f;
    float p[4][4];
    float ps = 0.f;
#pragma unroll
    for (int blk = 0; blk < 4; ++blk)
#pragma unroll
      for (int j = 0; j < 4; ++j) {
        float pv = __builtin_amdgcn_exp2f(__builtin_fmaf(sb[blk][j], 1.44269504f, -em));
        p[blk][j] = pv;
        ps += pv;
      }
    l += ps;

    __builtin_amdgcn_s_setprio(1);
#pragma unroll
    for (int s2 = 0; s2 < 2; ++s2) {
      u32x4 pw = { cvtpk(p[2 * s2][0], p[2 * s2][1]),
                   cvtpk(p[2 * s2][2], p[2 * s2][3]),
                   cvtpk(p[2 * s2 + 1][0], p[2 * s2 + 1][1]),
                   cvtpk(p[2 * s2 + 1][2], p[2 * s2 + 1][3]) };
      bf16x8 pb = __builtin_bit_cast(bf16x8, pw);
      int cl = s2 ? vx2 : vx0;
      int ch = s2 ? vx3 : vx1;
#pragma unroll
      for (int dblk = 0; dblk < 4; ++dblk) {
        uint2 lo = *(const uint2*)(Vb + vbase + dblk * 2048 + cl);
        uint2 hi = *(const uint2*)(Vb + vbase + dblk * 2048 + ch);
        bf16x8 va = __builtin_bit_cast(bf16x8, u32x4{ lo.x, lo.y, hi.x, hi.y });
        o[dblk] = mfma16(va, pb, o[dblk]);
      }
    }
    __builtin_amdgcn_s_setprio(0);

    __syncthreads();
    cur ^= 1;
  }

  float lt = l + __shfl_xor(l, 16);
  lt += __shfl_xor(lt, 32);
  float inv = 1.0f / lt;
  u16* orow = AO + ((size_t)b * 2048 + q0 + l15) * 1024 + h * 64 + 4 * g;
#pragma unroll
  for (int dblk = 0; dblk < 4; ++dblk) {
    u32x2 ov = { cvtpk(o[dblk][0] * inv, o[dblk][1] * inv),
                 cvtpk(o[dblk][2] * inv, o[dblk][3] * inv) };
    *(u32x2*)(orow + dblk * 16) = ov;
  }
}

// ---- launcher ---------------------------------------------------------------
extern "C" void kernel_launch(void* const* d_in, const int* in_sizes, int n_in,
                              void* d_out, int out_size, void* d_ws, size_t ws_size,
                              hipStream_t stream) {
  (void)in_sizes; (void)n_in; (void)out_size; (void)ws_size;
  const float* x     = (const float*)d_in[0];
  const float* Wqkv  = (const float*)d_in[1];
  const float* bqkv  = (const float*)d_in[2];
  const float* Wproj = (const float*)d_in[3];
  const float* bproj = (const float*)d_in[4];
  const int*   pos   = (const int*)d_in[5];

  char* ws = (char*)d_ws;
  u16*   XB     = (u16*)(ws + 0);
  u16*   WQKVT  = (u16*)(ws + 8388608);
  u16*   WPROJT = (u16*)(ws + 14680064);
  u16*   QR     = (u16*)(ws + 41943040);
  u16*   KR     = (u16*)(ws + 50331648);
  u16*   VT     = (u16*)(ws + 58720256);
  u16*   AO     = (u16*)(ws + 67108864);
  float* SIN    = (float*)(ws + 75497472);
  float* COS    = (float*)(ws + 75759616);

  k_prep<<<6400, 256, 0, stream>>>(x, XB, Wqkv, WQKVT, Wproj, WPROJT, pos, SIN, COS);
  k_gemm_qkv<<<32 * 24, 256, 0, stream>>>(XB, WQKVT, bqkv, QR, KR, VT, SIN, COS);
  k_attn<<<1024, 256, 0, stream>>>(QR, KR, VT, AO);
  k_gemm_proj<<<512, 128, 0, stream>>>(AO, WPROJT, bproj, (float*)d_out);
}

// Round 19
// 110.962 us; speedup vs baseline: 1.0840x; 1.0034x over previous
//
#include <hip/hip_runtime.h>
#include <hip/hip_bf16.h>
#include <stdint.h>

#define DEV __device__ __forceinline__

typedef unsigned short u16;
typedef unsigned int   u32;
typedef __attribute__((ext_vector_type(8))) short bf16x8;   // 8 bf16 = 4 VGPRs
typedef __attribute__((ext_vector_type(4))) float f32x4;
typedef __attribute__((ext_vector_type(4))) u32   u32x4;
typedef __attribute__((ext_vector_type(2))) u32   u32x2;

// ---- numeric helpers -------------------------------------------------------
DEV u16 f2bf(float f) {            // RNE f32 -> bf16
  u32 u = __builtin_bit_cast(u32, f);
  u = (u + 0x7fffu + ((u >> 16) & 1u)) >> 16;
  return (u16)u;
}
DEV float bf2f(u16 h) { return __builtin_bit_cast(float, (u32)h << 16); }
DEV u32 pk2(float a, float b) {    // pack 2 f32 -> 2 bf16 in one u32 (RNE)
  u32 x = __builtin_bit_cast(u32, a), y = __builtin_bit_cast(u32, b);
  x = (x + 0x7fffu + ((x >> 16) & 1u)) >> 16;
  y = (y + 0x7fffu + ((y >> 16) & 1u)) >> 16;
  return x | (y << 16);
}
DEV u32 cvtpk(float lo, float hi) {  // 1-instr RNE pack (same semantics as pk2)
  u32 r;
  asm("v_cvt_pk_bf16_f32 %0, %1, %2" : "=v"(r) : "v"(lo), "v"(hi));
  return r;
}
DEV f32x4 mfma16(bf16x8 a, bf16x8 b, f32x4 c) {
  return __builtin_amdgcn_mfma_f32_16x16x32_bf16(a, b, c, 0, 0, 0);
}
DEV void gload16(const void* g, void* l) {   // global -> LDS direct, 16B/lane
  __builtin_amdgcn_global_load_lds(
      (const __attribute__((address_space(1))) void*)g,
      (__attribute__((address_space(3))) void*)l, 16, 0, 0);
}

// ---- problem constants -----------------------------------------------------
// B=2 T=2048 DIM=1024 HEADS=16 HEAD_DIM=64; tokens = 4096
// workspace layout (bytes):
//  XB      0         x as bf16            [4096][1024]
//  WQKVT   8388608   Wqkv^T bf16          [3072][1024]
//  WPROJT  14680064  Wproj^T bf16         [1024][1024]
//  QR      41943040  roped*scale Q bf16   [32][2048][64]
//  KR      50331648  roped K bf16         [32][2048][64]
//  VT      58720256  V^T bf16             [32][64][2048]
//  AO      67108864  attn out bf16        [4096][1024]
//  SIN     75497472  f32 [2048][32]
//  COS     75759616  f32 [2048][32]

// ---- merged prep kernel ----------------------------------------------------
__global__ __launch_bounds__(256) void k_prep(const float* __restrict__ x,
                                              u16* __restrict__ XB,
                                              const float* __restrict__ Wqkv,
                                              u16* __restrict__ WQKVT,
                                              const float* __restrict__ Wproj,
                                              u16* __restrict__ WPROJT,
                                              const int* __restrict__ posp,
                                              float* __restrict__ sint,
                                              float* __restrict__ cost) {
  __shared__ float t[32][33];
  int bid = blockIdx.x;
  int tid = threadIdx.x;

  if (bid < 2048) {                        // ---- cvt x -> bf16
    size_t i = ((size_t)bid * 256 + tid) * 8;
    float4 a = *(const float4*)(x + i);
    float4 b = *(const float4*)(x + i + 4);
    u32x4 o = { pk2(a.x, a.y), pk2(a.z, a.w), pk2(b.x, b.y), pk2(b.z, b.w) };
    *(u32x4*)(XB + i) = o;
    return;
  }
  if (bid < 6144) {                        // ---- W transpose+cvt
    const float* W; u16* WT; int Ndim, idx;
    if (bid < 5120) { W = Wqkv;  WT = WQKVT;  Ndim = 3072; idx = bid - 2048; }
    else            { W = Wproj; WT = WPROJT; Ndim = 1024; idx = bid - 5120; }
    int bk = idx & 31;
    int bn = idx >> 5;
    int k0 = bk * 32, n0 = bn * 32;
    int tx = tid & 31, ty = tid >> 5;      // ty 0..7
#pragma unroll
    for (int i = 0; i < 4; ++i)
      t[ty + 8 * i][tx] = W[(size_t)(k0 + ty + 8 * i) * Ndim + n0 + tx];
    __syncthreads();
#pragma unroll
    for (int i = 0; i < 4; ++i) {
      int n = ty + 8 * i;
      WT[(size_t)(n0 + n) * 1024 + k0 + tx] = f2bf(t[tx][n]);
    }
    return;
  }
  // ---- rope tables
  int i = (bid - 6144) * 256 + tid;        // 65536 = 2048*32
  int tt = i >> 5, d = i & 31;
  float theta = exp2f(-(float)d * (13.2877123795494f / 32.0f));
  float ang = (float)(posp[0] + tt) * theta;
  sint[i] = sinf(ang);
  cost[i] = cosf(ang);
}

// ---- QKV GEMM, fused RoPE/V-transpose, LDS-coalesced epilogue --------------
// R19: L2-locality grid swizzle. Blocks processed in 4bm x 8bn super-chunks:
// each 32-block chunk touches 4 A-panels + 8 B-panels = 3MB (L2-resident per
// XCD) -> L3 traffic ~384MB -> ~72MB (XB read 3x not 24x, W 8x not 32x).
// Main loop + epilogue = R18 (m97 single-barrier + LDS-staged coalesced out).
__global__ __launch_bounds__(256, 3) void k_gemm_qkv(const u16* __restrict__ A,
                                                     const u16* __restrict__ BT,
                                                     const float* __restrict__ bias,
                                                     u16* __restrict__ QR,
                                                     u16* __restrict__ KR,
                                                     u16* __restrict__ VT,
                                                     const float* __restrict__ sint,
                                                     const float* __restrict__ cost) {
  constexpr int K = 1024;
  int idx = blockIdx.x;                 // 0..767
  int chunk = idx >> 5;                 // 0..23 (super-chunk of 4bm x 8bn)
  int c5 = idx & 31;
  int bm = (chunk & 7) * 4 + (c5 & 3);  // 0..31
  int bn = (chunk >> 3) * 8 + (c5 >> 2);// 0..23
  int m0 = bm * 128, n0 = bn * 128;
  int tid = threadIdx.x, lane = tid & 63, w = tid >> 6;
  int g = lane >> 4, l15 = lane & 15;
  int wr = w >> 1, wc = w & 1;

  __shared__ u16 smem[16384];           // 32KB: A dbuf | B dbuf, reused as stg

  f32x4 acc[4][4] = {};

  int rowW = w * 16 + (lane >> 2);
  int cSrc = (lane & 3) ^ ((lane >> 3) & 3);
  const u16* Ag0 = A  + (size_t)(m0 + rowW) * K + cSrc * 8;
  const u16* Ag1 = A  + (size_t)(m0 + 64 + rowW) * K + cSrc * 8;
  const u16* Bg0 = BT + (size_t)(n0 + rowW) * K + cSrc * 8;
  const u16* Bg1 = BT + (size_t)(n0 + 64 + rowW) * K + cSrc * 8;

  auto stage = [&](int k0, int buf) {
    char* Ab = (char*)(smem + buf * 4096);
    char* Bb = (char*)(smem + 8192 + buf * 4096);
    gload16(Ag0 + k0, Ab + w * 1024);
    gload16(Ag1 + k0, Ab + 4096 + w * 1024);
    gload16(Bg0 + k0, Bb + w * 1024);
    gload16(Bg1 + k0, Bb + 4096 + w * 1024);
  };

  stage(0, 0);
  __syncthreads();
  int cur = 0;

#pragma unroll 1
  for (int it = 0; it < 32; ++it) {
    if (it + 1 < 32) stage((it + 1) * 32, cur ^ 1);  // loads fly under compute
    const char* Ab = (const char*)(smem + cur * 4096);
    const char* Bb = (const char*)(smem + 8192 + cur * 4096);
    bf16x8 af[4], bf_[4];
#pragma unroll
    for (int m = 0; m < 4; ++m) {
      int r = wr * 64 + m * 16 + l15;
      af[m] = *(const bf16x8*)(Ab + r * 64 + ((g ^ ((r >> 1) & 3)) << 4));
    }
#pragma unroll
    for (int n = 0; n < 4; ++n) {
      int r = wc * 64 + n * 16 + l15;
      bf_[n] = *(const bf16x8*)(Bb + r * 64 + ((g ^ ((r >> 1) & 3)) << 4));
    }
#pragma unroll
    for (int m = 0; m < 4; ++m)
#pragma unroll
      for (int n = 0; n < 4; ++n)
        acc[m][n] = mfma16(af[m], bf_[n], acc[m][n]);
    __syncthreads();                    // single barrier: drains loads + reads
    cur ^= 1;
  }
  // K-loop done; smem dead -> reuse as 128x128 bf16 staging tile.
  int bq = m0 >> 11;                    // batch index (uniform per tile)

  if (bn >= 16) {
    // ---- V phase 1: packed token-quads into stg[h*64+d][t_local] (swizzled)
#pragma unroll
    for (int m = 0; m < 4; ++m) {
      int tl = wr * 64 + m * 16 + 4 * g;          // t_local, multiple of 4
#pragma unroll
      for (int n = 0; n < 4; ++n) {
        int colv = n0 + wc * 64 + n * 16 + l15 - 2048;
        float bv = bias[colv + 2048];
        int row = ((colv >> 6) & 1) * 64 + (colv & 63);  // h_local*64 + d
        int gr = ((tl >> 3) ^ (row & 7)) << 3;           // swizzled granule
        u32x2 o = { pk2(acc[m][n][0] + bv, acc[m][n][1] + bv),
                    pk2(acc[m][n][2] + bv, acc[m][n][3] + bv) };
        *(u32x2*)&smem[row * 128 + gr + (tl & 7)] = o;
      }
    }
  } else {
    // ---- Q/K phase 1: roped values into stg[t_local][h_local*64+outf]
    bool isQ = (bn < 8);
    int cofs = isQ ? 0 : 1024;
    float sc = isQ ? 0.125f : 1.0f;
#pragma unroll
    for (int m = 0; m < 4; ++m) {
      int rowb = m0 + wr * 64 + m * 16 + 4 * g;
#pragma unroll
      for (int n = 0; n < 4; ++n) {
        int col = n0 + wc * 64 + n * 16 + l15 - cofs;
        float bv = bias[col + cofs];
        int f = col & 63;
        int hl = (col >> 6) & 1;
        int dp = f >> 1;
        int outf = (f & 1) ? (32 + dp) : dp;
        int cq = hl * 64 + outf;                  // natural col 0..127
#pragma unroll
        for (int j = 0; j < 4; ++j) {
          int row = (rowb + j) & 127;             // t_local
          float v = acc[m][n][j] + bv;
          float pv = __shfl_xor(v, 1);
          float sn = sint[((rowb + j) & 2047) * 32 + dp];
          float cs = cost[((rowb + j) & 2047) * 32 + dp];
          float out = (f & 1) ? (pv * sn + v * cs) : (v * cs - pv * sn);
          int gr = ((cq >> 3) ^ (row & 7)) << 3;  // swizzled granule
          smem[row * 128 + gr + (cq & 7)] = f2bf(sc * out);
        }
      }
    }
  }
  __syncthreads();

  // ---- phase 2: coalesced read-out. 128 rows x 16 granules of 16B.
#pragma unroll
  for (int i = 0; i < 8; ++i) {
    int slot = i * 256 + tid;
    int row = slot >> 4;                          // 0..127
    int ch = slot & 15;                           // natural granule
    bf16x8 val = *(const bf16x8*)&smem[row * 128 + ((ch ^ (row & 7)) << 3)];
    if (bn >= 16) {
      int hl = row >> 6, d = row & 63;
      int bh = bq * 16 + (bn - 16) * 2 + hl;
      int t0 = m0 & 2047;
      *(bf16x8*)(VT + ((size_t)bh * 64 + d) * 2048 + t0 + ch * 8) = val;
    } else {
      bool isQ = (bn < 8);
      int hl = ch >> 3, cc = ch & 7;
      int bh = bq * 16 + (isQ ? bn * 2 : (bn - 8) * 2) + hl;
      int tt = (m0 + row) & 2047;
      u16* OUT = isQ ? QR : KR;
      *(bf16x8*)(OUT + ((size_t)bh * 2048 + tt) * 64 + cc * 8) = val;
    }
  }
}

// ---- proj GEMM v2: 64x128 tiles, 2 waves, 2 blocks/CU (R16, unchanged) -----
__global__ __launch_bounds__(128) void k_gemm_proj(const u16* __restrict__ A,
                                                   const u16* __restrict__ BT,
                                                   const float* __restrict__ bias,
                                                   float* __restrict__ Cout) {
  constexpr int K = 1024, N = 1024;
  int bm = blockIdx.x >> 3;           // 0..63
  int bn = blockIdx.x & 7;            // 0..7
  int m0 = bm * 64, n0 = bn * 128;
  int tid = threadIdx.x, lane = tid & 63, w = tid >> 6;  // w in {0,1}
  int g = lane >> 4, l15 = lane & 15;

  __shared__ u16 Alds[2][64 * 32];    // 4KB per buf
  __shared__ u16 Blds[2][128 * 32];   // 8KB per buf

  f32x4 acc[4][4] = {};

  int rT = tid >> 2;                  // 0..31
  int cT = tid & 3;
  const u16* AgBase = A  + (size_t)m0 * K;
  const u16* BgBase = BT + (size_t)n0 * K;

  auto stage = [&](int k0, int buf) {
#pragma unroll
    for (int i = 0; i < 2; ++i) {     // A: 64 rows x 4 chunks
      int row = i * 32 + rT;
      int csrc = cT ^ ((row >> 1) & 3);
      gload16(AgBase + (size_t)row * K + k0 + csrc * 8,
              (char*)&Alds[buf][0] + i * 2048 + w * 1024);
    }
#pragma unroll
    for (int i = 0; i < 4; ++i) {     // B: 128 rows x 4 chunks
      int row = i * 32 + rT;
      int csrc = cT ^ ((row >> 1) & 3);
      gload16(BgBase + (size_t)row * K + k0 + csrc * 8,
              (char*)&Blds[buf][0] + i * 2048 + w * 1024);
    }
  };

  stage(0, 0);
  __syncthreads();
  int cur = 0;

#pragma unroll 1
  for (int it = 0; it < 32; ++it) {
    if (it + 1 < 32) stage((it + 1) * 32, cur ^ 1);
    const char* Ab = (const char*)&Alds[cur][0];
    const char* Bb = (const char*)&Blds[cur][0];
    bf16x8 af[4], bf_[4];
#pragma unroll
    for (int m = 0; m < 4; ++m) {
      int r = m * 16 + l15;
      af[m] = *(const bf16x8*)(Ab + r * 64 + ((g ^ ((r >> 1) & 3)) << 4));
    }
#pragma unroll
    for (int n = 0; n < 4; ++n) {
      int r = w * 64 + n * 16 + l15;
      bf_[n] = *(const bf16x8*)(Bb + r * 64 + ((g ^ ((r >> 1) & 3)) << 4));
    }
#pragma unroll
    for (int m = 0; m < 4; ++m)
#pragma unroll
      for (int n = 0; n < 4; ++n)
        acc[m][n] = mfma16(af[m], bf_[n], acc[m][n]);
    __syncthreads();
    cur ^= 1;
  }

#pragma unroll
  for (int m = 0; m < 4; ++m) {
    int rowb = m0 + m * 16 + 4 * g;
#pragma unroll
    for (int n = 0; n < 4; ++n) {
      int col = n0 + w * 64 + n * 16 + l15;
      float bv = bias[col];
#pragma unroll
      for (int j = 0; j < 4; ++j)
        Cout[(size_t)(rowb + j) * N + col] = acc[m][n][j] + bv;
    }
  }
}

// ---- causal flash attention (R5/R13 verbatim — proven 46 us) ---------------
__global__ __launch_bounds__(256, 4) void k_attn(const u16* __restrict__ QR,
                                                 const u16* __restrict__ KR,
                                                 const u16* __restrict__ VT,
                                                 u16* __restrict__ AO) {
  int tid = threadIdx.x;
  int w = tid >> 6, lane = tid & 63;
  int g = lane >> 4, l15 = lane & 15;
  int l7 = l15 & 7, g2 = g >> 1;

  int idx = blockIdx.x;
  int tt = 31 - (idx >> 5);          // q-tile 31..0 (heavy first)
  int bh = idx & 31;                 // bh mod 8 = XCD slot -> 4 bh per XCD
  int nt = tt + 1;                   // 64-key tiles to process
  int b = bh >> 4, h = bh & 15;
  int q0 = tt * 64 + w * 16;         // wave's 16-row subtile
  int qa = q0 + l15;

  const u16* Kg = KR + (size_t)bh * 2048 * 64;
  const u16* Vg = VT + (size_t)bh * 64 * 2048;

  __shared__ u16 Klds[2][64 * 64];   // 8KB/buf: [key][64 d], swizzled
  __shared__ u16 Vlds[2][64 * 64];   // 8KB/buf: [d][64 key], swizzled

  const u16* Qr = QR + ((size_t)bh * 2048 + q0 + l15) * 64 + 8 * g;
  bf16x8 qf0 = *(const bf16x8*)(Qr);
  bf16x8 qf1 = *(const bf16x8*)(Qr + 32);

  f32x4 o[4] = {};
  float m = -1e30f, l = 0.f;

  // hoisted LDS read constants
  int kx0 = ((g ^ l7) << 4);                 // K frag chunk offsets (bytes)
  int kx1 = (((4 + g) ^ l7) << 4);
  int vx0 = ((g2 ^ l7) << 4);                // V chunks s2=0: {g2, 2+g2}
  int vx1 = (((2 + g2) ^ l7) << 4);
  int vx2 = (((4 + g2) ^ l7) << 4);          // s2=1: {4+g2, 6+g2}
  int vx3 = (((6 + g2) ^ l7) << 4);
  int vbase = l15 * 128 + ((g & 1) << 3);

  // staging: 256 threads cover 64 rows x 8 chunks in 2 issues (K and V each)
  int rstg = lane >> 3;                      // 0..7
  int cswz = (lane & 7) ^ rstg;              // pre-swizzled source chunk

  auto stage = [&](int kt, int buf) {
#pragma unroll
    for (int j = 0; j < 2; ++j) {
      int r = j * 32 + w * 8 + rstg;
      gload16(Kg + (size_t)(kt * 64 + r) * 64 + cswz * 8,
              &Klds[buf][(j * 32 + w * 8) * 64]);
      gload16(Vg + (size_t)r * 2048 + kt * 64 + cswz * 8,
              &Vlds[buf][(j * 32 + w * 8) * 64]);
    }
  };

  stage(0, 0);
  __syncthreads();
  int cur = 0;

  for (int t = 0; t < nt; ++t) {
    if (t + 1 < nt) stage(t + 1, cur ^ 1);   // async prefetch next tile
    const char* Kb = (const char*)&Klds[cur][0];
    const char* Vb = (const char*)&Vlds[cur][0];

    // S^T = K.Q (64 keys x 16 q)
    f32x4 sb[4];
    __builtin_amdgcn_s_setprio(1);
#pragma unroll
    for (int blk = 0; blk < 4; ++blk) {
      const char* kb = Kb + blk * 2048 + l15 * 128;
      bf16x8 k0 = *(const bf16x8*)(kb + kx0);
      bf16x8 k1 = *(const bf16x8*)(kb + kx1);
      f32x4 z = { 0.f, 0.f, 0.f, 0.f };
      z = mfma16(k0, qf0, z);
      sb[blk] = mfma16(k1, qf1, z);
    }
    __builtin_amdgcn_s_setprio(0);

    if (t == nt - 1) {               // causal mask, final tile only
      int tk0 = t * 64;
#pragma unroll
      for (int blk = 0; blk < 4; ++blk)
#pragma unroll
        for (int j = 0; j < 4; ++j) {
          int tk = tk0 + blk * 16 + 4 * g + j;
          if (tk > qa) sb[blk][j] = -1e30f;
        }
    }

    // online softmax (defer-max) + PV
    float mx = fmaxf(fmaxf(fmaxf(sb[0][0], sb[0][1]), fmaxf(sb[0][2], sb[0][3])),
                     fmaxf(fmaxf(sb[1][0], sb[1][1]), fmaxf(sb[1][2], sb[1][3])));
    mx = fmaxf(mx, fmaxf(fmaxf(fmaxf(sb[2][0], sb[2][1]), fmaxf(sb[2][2], sb[2][3])),
                         fmaxf(fmaxf(sb[3][0], sb[3][1]), fmaxf(sb[3][2], sb[3][3]))));
    mx = fmaxf(mx, __shfl_xor(mx, 16));
    mx = fmaxf(mx, __shfl_xor(mx, 32));
    if (!__all(mx <= m + 8.0f)) {
      float mnew = fmaxf(m, mx);
      float a = __builtin_amdgcn_exp2f((m - mnew) * 1.44269504f);
      l *= a;
#pragma unroll
      for (int d = 0; d < 4; ++d) o[d] *= a;
      m = mnew;
    }
    float em = m * 1.44269504f;
    float p[4][4];
    float ps = 0.f;
#pragma unroll
    for (int blk = 0; blk < 4; ++blk)
#pragma unroll
      for (int j = 0; j < 4; ++j) {
        float pv = __builtin_amdgcn_exp2f(__builtin_fmaf(sb[blk][j], 1.44269504f, -em));
        p[blk][j] = pv;
        ps += pv;
      }
    l += ps;

    __builtin_amdgcn_s_setprio(1);
#pragma unroll
    for (int s2 = 0; s2 < 2; ++s2) {
      u32x4 pw = { cvtpk(p[2 * s2][0], p[2 * s2][1]),
                   cvtpk(p[2 * s2][2], p[2 * s2][3]),
                   cvtpk(p[2 * s2 + 1][0], p[2 * s2 + 1][1]),
                   cvtpk(p[2 * s2 + 1][2], p[2 * s2 + 1][3]) };
      bf16x8 pb = __builtin_bit_cast(bf16x8, pw);
      int cl = s2 ? vx2 : vx0;
      int ch = s2 ? vx3 : vx1;
#pragma unroll
      for (int dblk = 0; dblk < 4; ++dblk) {
        uint2 lo = *(const uint2*)(Vb + vbase + dblk * 2048 + cl);
        uint2 hi = *(const uint2*)(Vb + vbase + dblk * 2048 + ch);
        bf16x8 va = __builtin_bit_cast(bf16x8, u32x4{ lo.x, lo.y, hi.x, hi.y });
        o[dblk] = mfma16(va, pb, o[dblk]);
      }
    }
    __builtin_amdgcn_s_setprio(0);

    __syncthreads();
    cur ^= 1;
  }

  float lt = l + __shfl_xor(l, 16);
  lt += __shfl_xor(lt, 32);
  float inv = 1.0f / lt;
  u16* orow = AO + ((size_t)b * 2048 + q0 + l15) * 1024 + h * 64 + 4 * g;
#pragma unroll
  for (int dblk = 0; dblk < 4; ++dblk) {
    u32x2 ov = { cvtpk(o[dblk][0] * inv, o[dblk][1] * inv),
                 cvtpk(o[dblk][2] * inv, o[dblk][3] * inv) };
    *(u32x2*)(orow + dblk * 16) = ov;
  }
}

// ---- launcher ---------------------------------------------------------------
extern "C" void kernel_launch(void* const* d_in, const int* in_sizes, int n_in,
                              void* d_out, int out_size, void* d_ws, size_t ws_size,
                              hipStream_t stream) {
  (void)in_sizes; (void)n_in; (void)out_size; (void)ws_size;
  const float* x     = (const float*)d_in[0];
  const float* Wqkv  = (const float*)d_in[1];
  const float* bqkv  = (const float*)d_in[2];
  const float* Wproj = (const float*)d_in[3];
  const float* bproj = (const float*)d_in[4];
  const int*   pos   = (const int*)d_in[5];

  char* ws = (char*)d_ws;
  u16*   XB     = (u16*)(ws + 0);
  u16*   WQKVT  = (u16*)(ws + 8388608);
  u16*   WPROJT = (u16*)(ws + 14680064);
  u16*   QR     = (u16*)(ws + 41943040);
  u16*   KR     = (u16*)(ws + 50331648);
  u16*   VT     = (u16*)(ws + 58720256);
  u16*   AO     = (u16*)(ws + 67108864);
  float* SIN    = (float*)(ws + 75497472);
  float* COS    = (float*)(ws + 75759616);

  k_prep<<<6400, 256, 0, stream>>>(x, XB, Wqkv, WQKVT, Wproj, WPROJT, pos, SIN, COS);
  k_gemm_qkv<<<32 * 24, 256, 0, stream>>>(XB, WQKVT, bqkv, QR, KR, VT, SIN, COS);
  k_attn<<<1024, 256, 0, stream>>>(QR, KR, VT, AO);
  k_gemm_proj<<<512, 128, 0, stream>>>(AO, WPROJT, bproj, (float*)d_out);
}